// Round 3
// baseline (193.814 us; speedup 1.0000x reference)
//
#include <hip/hip_runtime.h>
#include <hip/hip_bf16.h>

typedef unsigned short u16;
typedef __attribute__((ext_vector_type(8))) short  bf16x8;
typedef __attribute__((ext_vector_type(4))) float  fx4;
typedef __attribute__((ext_vector_type(16))) float fx16;

// flat offsets of TT cores in the packed kernel (reference iterates k=3..0 from idx 0)
#define OFF_C0 0       // core for k=3: [8 x 256]   core0[i4][a3*8+o4]
#define OFF_C1 2048    // core for k=2: [256 x 256] core1[i3*32+a3][a2*8+o3]
#define OFF_C2 67584   // core for k=1: [256 x 256] core2[i2*32+a2][a1*8+o2]
#define OFF_C3 133120  // core for k=0: [256 x 8]   core3[i1*32+a1][o1]

static __device__ __forceinline__ u16 f2bf(float f) {
  union { __hip_bfloat16 h; u16 u; } cv;
  cv.h = __float2bfloat16(f);
  return cv.u;
}
static __device__ __forceinline__ float bf2f(u16 u) {
  union { u16 u; __hip_bfloat16 h; } cv;
  cv.u = u;
  return __bfloat162float(cv.h);
}

// W34T[c][i34], c = a2*64 + o3*8 + o4 (2048 x 64 fp32)
__global__ void build_w34T(const float* __restrict__ ker, float* __restrict__ w34T) {
  int t = blockIdx.x * 256 + threadIdx.x;   // 131072 threads
  int i34 = t & 63, c = t >> 6;
  int a2 = c >> 6, o3 = (c >> 3) & 7, o4 = c & 7;
  int i3 = i34 >> 3, i4 = i34 & 7;
  float s = 0.f;
#pragma unroll 8
  for (int a3 = 0; a3 < 32; ++a3) {
    float k1 = ker[OFF_C1 + (i3 * 32 + a3) * 256 + a2 * 8 + o3];
    float k0 = ker[OFF_C0 + i4 * 256 + a3 * 8 + o4];
    s += k1 * k0;
  }
  w34T[c * 64 + i34] = s;
}

// W234t[(a1*64+o2*8+o3)*8 + o4][i234] = sum_a2 core2[i2*32+a2, a1*8+o2] * W34T[a2*64+o3*8+o4][i34]
__global__ void build_w234t2(const float* __restrict__ ker, const float* __restrict__ w34T,
                             u16* __restrict__ w234t) {
  int t = blockIdx.x * 256 + threadIdx.x;   // 131072 threads
  int i234 = t & 511, g = t >> 9;           // g = a1*8 + o3
  int a1 = g >> 3, o3 = g & 7;
  int i2 = i234 >> 6, i34 = i234 & 63;
  float acc[8][8];
#pragma unroll
  for (int a = 0; a < 8; ++a)
#pragma unroll
    for (int b = 0; b < 8; ++b) acc[a][b] = 0.f;
  for (int a2 = 0; a2 < 32; ++a2) {
    float w[8];
#pragma unroll
    for (int o4 = 0; o4 < 8; ++o4)
      w[o4] = w34T[(a2 * 64 + o3 * 8 + o4) * 64 + i34];
#pragma unroll
    for (int o2 = 0; o2 < 8; ++o2) {
      float c2 = ker[OFF_C2 + (i2 * 32 + a2) * 256 + a1 * 8 + o2];
#pragma unroll
      for (int o4 = 0; o4 < 8; ++o4) acc[o2][o4] += c2 * w[o4];
    }
  }
#pragma unroll
  for (int o2 = 0; o2 < 8; ++o2) {
    int cg = a1 * 64 + o2 * 8 + o3;
#pragma unroll
    for (int o4 = 0; o4 < 8; ++o4)
      w234t[(cg * 8 + o4) * 512 + i234] = f2bf(acc[o2][o4]);
  }
}

// Wt[j,i]: thread owns (j234, i234), reads each w234t element once, computes all 64 (i1,o1).
__global__ void build_wt2(const float* __restrict__ ker, const u16* __restrict__ w234t,
                          u16* __restrict__ wt) {
  int t = blockIdx.x * 256 + threadIdx.x;   // 262144 threads
  int i234 = t & 511, j234 = t >> 9;
  float acc[8][8];
#pragma unroll
  for (int a = 0; a < 8; ++a)
#pragma unroll
    for (int b = 0; b < 8; ++b) acc[a][b] = 0.f;
  for (int a1 = 0; a1 < 32; ++a1) {
    float w = bf2f(w234t[(a1 * 512 + j234) * 512 + i234]);
#pragma unroll
    for (int i1 = 0; i1 < 8; ++i1) {
      const float* c3 = ker + OFF_C3 + (i1 * 32 + a1) * 8;
#pragma unroll
      for (int o1 = 0; o1 < 8; ++o1) acc[i1][o1] += c3[o1] * w;
    }
  }
#pragma unroll
  for (int o1 = 0; o1 < 8; ++o1)
#pragma unroll
    for (int i1 = 0; i1 < 8; ++i1)
      wt[(size_t)(o1 * 512 + j234) * 4096 + i1 * 512 + i234] = f2bf(acc[i1][o1]);
}

// x (fp32) -> bf16, 8 elements/thread, 2097152 threads.
__global__ void x_to_bf16(const float* __restrict__ x, u16* __restrict__ xb) {
  int t = blockIdx.x * 256 + threadIdx.x;
  const fx4* p = (const fx4*)(x + (size_t)t * 8);
  fx4 v0 = p[0], v1 = p[1];
  u16 tmp[8];
#pragma unroll
  for (int q = 0; q < 4; ++q) tmp[q] = f2bf(v0[q]);
#pragma unroll
  for (int q = 0; q < 4; ++q) tmp[4 + q] = f2bf(v1[q]);
  typedef __attribute__((ext_vector_type(8))) u16 u16x8;
  *(u16x8*)(xb + (size_t)t * 8) = *(const u16x8*)tmp;
}

__device__ __forceinline__ void gld16(const u16* g, u16* l) {
  __builtin_amdgcn_global_load_lds((const __attribute__((address_space(1))) void*)g,
                                   (__attribute__((address_space(3))) void*)l, 16, 0, 0);
}

// C[4096,4096] = A * Bt^T + bias (bf16 in, fp32 out).
// 256x256 tile, BK=32, 8 waves (2Mx4N), per-wave 128x64 via 4x2 frags of 32x32x16 MFMA.
// 4 LDS buffers/operand (128 KiB), stage distance 3, counted vmcnt(8), raw s_barrier,
// XOR slot swizzle (inverse-swizzled global source + swizzled ds_read, rule #21).
__global__ __launch_bounds__(512, 2) void gemm_bt3(const u16* __restrict__ A, const u16* __restrict__ Bt,
                                                   const float* __restrict__ bias, float* __restrict__ C) {
  __shared__ __align__(16) u16 sh[65536];  // bytes: A bufs [0,64K), B bufs [64K,128K)

  const int tid = threadIdx.x;
  const int lane = tid & 63;
  const int wave = tid >> 6;
  const int wm = wave >> 2, wn = wave & 3;
  const int l32 = lane & 31, hk = lane >> 5;

  // XCD-aware swizzle (256 blocks, 256%8==0)
  const int bid = blockIdx.x;
  const int wg = (bid & 7) * 32 + (bid >> 3);
  const int bm = (wg >> 4) * 256, bn = (wg & 15) * 256;

  // staging: thread -> row tid>>2 (+128), linear LDS slot tid&3; global source slot pre-swizzled
  const int srow = tid >> 2;
  const int sco = (((tid & 3) ^ ((tid >> 3) & 3)) * 8);
  const size_t agA0 = (size_t)(bm + srow) * 4096 + sco;
  const size_t agA1 = agA0 + (size_t)128 * 4096;
  const size_t agB0 = (size_t)(bn + srow) * 4096 + sco;
  const size_t agB1 = agB0 + (size_t)128 * 4096;
  const int ldsW = wave * 512;  // elements

  // fragment read element-offsets within a 16KB buffer (row*32 + swizzled slot*8)
  // A frag (m,kk): row R = wm*128 + m*32 + l32, slot = (kk*2+hk) ^ ((R>>1)&3)
  int aoff[4][2], boff[2][2];
#pragma unroll
  for (int m = 0; m < 4; ++m) {
    const int R = wm * 128 + m * 32 + l32;
#pragma unroll
    for (int kk = 0; kk < 2; ++kk)
      aoff[m][kk] = R * 32 + (((kk * 2 + hk) ^ ((R >> 1) & 3)) * 8);
  }
#pragma unroll
  for (int n = 0; n < 2; ++n) {
    const int R = wn * 64 + n * 32 + l32;
#pragma unroll
    for (int kk = 0; kk < 2; ++kk)
      boff[n][kk] = R * 32 + (((kk * 2 + hk) ^ ((R >> 1) & 3)) * 8);
  }

  fx16 acc[4][2];
#pragma unroll
  for (int m = 0; m < 4; ++m)
#pragma unroll
    for (int n = 0; n < 2; ++n)
#pragma unroll
      for (int q = 0; q < 16; ++q) acc[m][n][q] = 0.f;

  // prologue: stage tiles 0,1,2; wait tile0 landed (12 issued, drop to 8)
  for (int pt = 0; pt < 3; ++pt) {
    u16* Aq = sh + pt * 8192;
    u16* Bq = sh + 32768 + pt * 8192;
    gld16(A + agA0 + pt * 32, Aq + ldsW);
    gld16(A + agA1 + pt * 32, Aq + ldsW + 4096);
    gld16(Bt + agB0 + pt * 32, Bq + ldsW);
    gld16(Bt + agB1 + pt * 32, Bq + ldsW + 4096);
  }
  asm volatile("s_waitcnt vmcnt(8)" ::: "memory");
  __builtin_amdgcn_s_barrier();

  for (int t = 0; t < 128; ++t) {
    u16* Ap = sh + (t & 3) * 8192;
    u16* Bp = sh + 32768 + (t & 3) * 8192;
    u16* Aq = sh + ((t + 3) & 3) * 8192;
    u16* Bq = sh + 32768 + ((t + 3) & 3) * 8192;
    const size_t ko = (size_t)(((t + 3) & 127) * 32);  // wraparound tail: constant vmcnt imm

    // ---- phase A: kk=0 (6 ds_read_b128, stage A pair, 8 MFMA) ----
    bf16x8 av[4], bv[2];
#pragma unroll
    for (int m = 0; m < 4; ++m) av[m] = *(const bf16x8*)(Ap + aoff[m][0]);
#pragma unroll
    for (int n = 0; n < 2; ++n) bv[n] = *(const bf16x8*)(Bp + boff[n][0]);
    gld16(A + agA0 + ko, Aq + ldsW);
    gld16(A + agA1 + ko, Aq + ldsW + 4096);
    __builtin_amdgcn_s_barrier();
    __builtin_amdgcn_s_setprio(1);
#pragma unroll
    for (int m = 0; m < 4; ++m)
#pragma unroll
      for (int n = 0; n < 2; ++n)
        acc[m][n] = __builtin_amdgcn_mfma_f32_32x32x16_bf16(av[m], bv[n], acc[m][n], 0, 0, 0);
    __builtin_amdgcn_s_setprio(0);
    __builtin_amdgcn_s_barrier();

    // ---- phase B: kk=1 ----
    bf16x8 aw[4], bw[2];
#pragma unroll
    for (int m = 0; m < 4; ++m) aw[m] = *(const bf16x8*)(Ap + aoff[m][1]);
#pragma unroll
    for (int n = 0; n < 2; ++n) bw[n] = *(const bf16x8*)(Bp + boff[n][1]);
    gld16(Bt + agB0 + ko, Bq + ldsW);
    gld16(Bt + agB1 + ko, Bq + ldsW + 4096);
    __builtin_amdgcn_s_barrier();
    __builtin_amdgcn_s_setprio(1);
#pragma unroll
    for (int m = 0; m < 4; ++m)
#pragma unroll
      for (int n = 0; n < 2; ++n)
        acc[m][n] = __builtin_amdgcn_mfma_f32_32x32x16_bf16(aw[m], bw[n], acc[m][n], 0, 0, 0);
    __builtin_amdgcn_s_setprio(0);
    // counted drain: retire tile staged at iter t-2 (needed at t+1); 8 stay in flight.
    asm volatile("s_waitcnt vmcnt(8)" ::: "memory");
    __builtin_amdgcn_s_barrier();
  }

  // epilogue: C/D layout col=lane&31, row=(reg&3)+8*(reg>>2)+4*(lane>>5)  [m74/m101]
#pragma unroll
  for (int n = 0; n < 2; ++n) {
    const int col = bn + wn * 64 + n * 32 + l32;
    const float bvl = bias[col];
#pragma unroll
    for (int m = 0; m < 4; ++m) {
      const int r0 = bm + wm * 128 + m * 32 + 4 * hk;
#pragma unroll
      for (int q = 0; q < 16; ++q) {
        const int row = r0 + (q & 3) + 8 * (q >> 2);
        C[(size_t)row * 4096 + col] = acc[m][n][q] + bvl;
      }
    }
  }
}

extern "C" void kernel_launch(void* const* d_in, const int* in_sizes, int n_in,
                              void* d_out, int out_size, void* d_ws, size_t ws_size,
                              hipStream_t stream) {
  const float* x    = (const float*)d_in[0];
  const float* ker  = (const float*)d_in[1];
  const float* bias = (const float*)d_in[2];
  float* out = (float*)d_out;

  char* ws = (char*)d_ws;
  u16*  xb    = (u16*)ws;                      // 32 MB  bf16 x
  u16*  wt    = (u16*)(ws + 33554432);         // 32 MB  bf16 W^T
  u16*  w234t = (u16*)(ws + 67108864);         // 16 MB  bf16 W234^T
  float* w34T = (float*)(ws + 83886080);       // 512 KB fp32 W34 transposed

  x_to_bf16   <<<8192, 256, 0, stream>>>(x, xb);
  build_w34T  <<<512, 256, 0, stream>>>(ker, w34T);
  build_w234t2<<<512, 256, 0, stream>>>(ker, w34T, w234t);
  build_wt2   <<<1024, 256, 0, stream>>>(ker, w234t, wt);
  gemm_bt3    <<<256, 512, 0, stream>>>(xb, wt, bias, out);
}

// Round 4
// 177.547 us; speedup vs baseline: 1.0916x; 1.0916x over previous
//
#include <hip/hip_runtime.h>
#include <hip/hip_bf16.h>

typedef unsigned short u16;
typedef __attribute__((ext_vector_type(8))) short  bf16x8;
typedef __attribute__((ext_vector_type(4))) float  fx4;

// flat offsets of TT cores in the packed kernel (reference iterates k=3..0 from idx 0)
#define OFF_C0 0       // core for k=3: [8 x 256]   core0[i4][a3*8+o4]
#define OFF_C1 2048    // core for k=2: [256 x 256] core1[i3*32+a3][a2*8+o3]
#define OFF_C2 67584   // core for k=1: [256 x 256] core2[i2*32+a2][a1*8+o2]
#define OFF_C3 133120  // core for k=0: [256 x 8]   core3[i1*32+a1][o1]

static __device__ __forceinline__ u16 f2bf(float f) {
  union { __hip_bfloat16 h; u16 u; } cv;
  cv.h = __float2bfloat16(f);
  return cv.u;
}
static __device__ __forceinline__ float bf2f(u16 u) {
  union { u16 u; __hip_bfloat16 h; } cv;
  cv.u = u;
  return __bfloat162float(cv.h);
}

// W34T[c][i34], c = a2*64 + o3*8 + o4 (2048 x 64 fp32)
__global__ void build_w34T(const float* __restrict__ ker, float* __restrict__ w34T) {
  int t = blockIdx.x * 256 + threadIdx.x;   // 131072 threads
  int i34 = t & 63, c = t >> 6;
  int a2 = c >> 6, o3 = (c >> 3) & 7, o4 = c & 7;
  int i3 = i34 >> 3, i4 = i34 & 7;
  float s = 0.f;
#pragma unroll 8
  for (int a3 = 0; a3 < 32; ++a3) {
    float k1 = ker[OFF_C1 + (i3 * 32 + a3) * 256 + a2 * 8 + o3];
    float k0 = ker[OFF_C0 + i4 * 256 + a3 * 8 + o4];
    s += k1 * k0;
  }
  w34T[c * 64 + i34] = s;
}

// W234t[(a1*64+o2*8+o3)*8 + o4][i234] = sum_a2 core2[i2*32+a2, a1*8+o2] * W34T[a2*64+o3*8+o4][i34]
__global__ void build_w234t2(const float* __restrict__ ker, const float* __restrict__ w34T,
                             u16* __restrict__ w234t) {
  int t = blockIdx.x * 256 + threadIdx.x;   // 131072 threads
  int i234 = t & 511, g = t >> 9;           // g = a1*8 + o3
  int a1 = g >> 3, o3 = g & 7;
  int i2 = i234 >> 6, i34 = i234 & 63;
  float acc[8][8];
#pragma unroll
  for (int a = 0; a < 8; ++a)
#pragma unroll
    for (int b = 0; b < 8; ++b) acc[a][b] = 0.f;
  for (int a2 = 0; a2 < 32; ++a2) {
    float w[8];
#pragma unroll
    for (int o4 = 0; o4 < 8; ++o4)
      w[o4] = w34T[(a2 * 64 + o3 * 8 + o4) * 64 + i34];
#pragma unroll
    for (int o2 = 0; o2 < 8; ++o2) {
      float c2 = ker[OFF_C2 + (i2 * 32 + a2) * 256 + a1 * 8 + o2];
#pragma unroll
      for (int o4 = 0; o4 < 8; ++o4) acc[o2][o4] += c2 * w[o4];
    }
  }
#pragma unroll
  for (int o2 = 0; o2 < 8; ++o2) {
    int cg = a1 * 64 + o2 * 8 + o3;
#pragma unroll
    for (int o4 = 0; o4 < 8; ++o4)
      w234t[(cg * 8 + o4) * 512 + i234] = f2bf(acc[o2][o4]);
  }
}

// Wt[j,i]: thread owns (j234, i234), reads each w234t element once, computes all 64 (i1,o1).
__global__ void build_wt2(const float* __restrict__ ker, const u16* __restrict__ w234t,
                          u16* __restrict__ wt) {
  int t = blockIdx.x * 256 + threadIdx.x;   // 262144 threads
  int i234 = t & 511, j234 = t >> 9;
  float acc[8][8];
#pragma unroll
  for (int a = 0; a < 8; ++a)
#pragma unroll
    for (int b = 0; b < 8; ++b) acc[a][b] = 0.f;
  for (int a1 = 0; a1 < 32; ++a1) {
    float w = bf2f(w234t[(a1 * 512 + j234) * 512 + i234]);
#pragma unroll
    for (int i1 = 0; i1 < 8; ++i1) {
      const float* c3 = ker + OFF_C3 + (i1 * 32 + a1) * 8;
#pragma unroll
      for (int o1 = 0; o1 < 8; ++o1) acc[i1][o1] += c3[o1] * w;
    }
  }
#pragma unroll
  for (int o1 = 0; o1 < 8; ++o1)
#pragma unroll
    for (int i1 = 0; i1 < 8; ++i1)
      wt[(size_t)(o1 * 512 + j234) * 4096 + i1 * 512 + i234] = f2bf(acc[i1][o1]);
}

// x (fp32) -> bf16, 8 elements/thread, 2097152 threads.
__global__ void x_to_bf16(const float* __restrict__ x, u16* __restrict__ xb) {
  int t = blockIdx.x * 256 + threadIdx.x;
  const fx4* p = (const fx4*)(x + (size_t)t * 8);
  fx4 v0 = p[0], v1 = p[1];
  u16 tmp[8];
#pragma unroll
  for (int q = 0; q < 4; ++q) tmp[q] = f2bf(v0[q]);
#pragma unroll
  for (int q = 0; q < 4; ++q) tmp[4 + q] = f2bf(v1[q]);
  typedef __attribute__((ext_vector_type(8))) u16 u16x8;
  *(u16x8*)(xb + (size_t)t * 8) = *(const u16x8*)tmp;
}

__device__ __forceinline__ void gld16(const u16* g, u16* l) {
  __builtin_amdgcn_global_load_lds((const __attribute__((address_space(1))) void*)g,
                                   (__attribute__((address_space(3))) void*)l, 16, 0, 0);
}

// C[4096,4096] = A * Bt^T + bias (bf16 in, fp32 out).
// 256x256 tile, BK=32, 8 waves (2Mx4N), per-wave 128x64 via 8x4 frags of 16x16x32 MFMA.
// 4 LDS buffers/operand (128 KiB), stage distance 3, counted vmcnt(8),
// ONE barrier per K-tile (waves free-run within tile; compiler emits counted lgkmcnt
// between ds_read and dependent MFMA). XOR slot swizzle identical to R1 (measured 0 conflicts).
__global__ __launch_bounds__(512, 2) void gemm_bt4(const u16* __restrict__ A, const u16* __restrict__ Bt,
                                                   const float* __restrict__ bias, float* __restrict__ C) {
  __shared__ __align__(16) u16 sh[65536];  // bytes: A bufs [0,64K), B bufs [64K,128K)

  const int tid = threadIdx.x;
  const int lane = tid & 63;
  const int wave = tid >> 6;
  const int wm = wave >> 2, wn = wave & 3;
  const int fr = lane & 15, fg = lane >> 4;

  // XCD-aware swizzle (256 blocks, 256%8==0 -> simple form valid)
  const int bid = blockIdx.x;
  const int wg = (bid & 7) * 32 + (bid >> 3);
  const int bm = (wg >> 4) * 256, bn = (wg & 15) * 256;

  // staging: thread -> row tid>>2 (+128 for 2nd load), slot tid&3; LDS dest linear (= tid*16B),
  // global source slot pre-swizzled: s ^ ((row>>1)&3)  (same for row and row+128)
  const int srow = tid >> 2;
  const int sco = (((tid & 3) ^ ((tid >> 3) & 3)) * 8);
  const size_t agA0 = (size_t)(bm + srow) * 4096 + sco;
  const size_t agA1 = agA0 + (size_t)128 * 4096;
  const size_t agB0 = (size_t)(bn + srow) * 4096 + sco;
  const size_t agB1 = agB0 + (size_t)128 * 4096;
  const int ldsW = wave * 512;  // elements

  fx4 acc[8][4];
#pragma unroll
  for (int m = 0; m < 8; ++m)
#pragma unroll
    for (int n = 0; n < 4; ++n) acc[m][n] = (fx4){0.f, 0.f, 0.f, 0.f};

  // prologue: stage tiles 0,1,2 (12 loads/thread); wait tile0 landed (drop oldest 4)
  for (int pt = 0; pt < 3; ++pt) {
    u16* Aq = sh + pt * 8192;
    u16* Bq = sh + 32768 + pt * 8192;
    gld16(A + agA0 + pt * 32, Aq + ldsW);
    gld16(A + agA1 + pt * 32, Aq + ldsW + 4096);
    gld16(Bt + agB0 + pt * 32, Bq + ldsW);
    gld16(Bt + agB1 + pt * 32, Bq + ldsW + 4096);
  }
  asm volatile("s_waitcnt vmcnt(8)" ::: "memory");
  __builtin_amdgcn_s_barrier();

  for (int t = 0; t < 128; ++t) {
    u16* Ap = sh + (t & 3) * 8192;
    u16* Bp = sh + 32768 + (t & 3) * 8192;
    u16* Aq = sh + ((t + 3) & 3) * 8192;
    u16* Bq = sh + 32768 + ((t + 3) & 3) * 8192;
    const size_t ko = (size_t)(((t + 3) & 127) * 32);  // wraparound tail: keeps vmcnt imm constant

    // issue ALL fragment reads for this tile up front (12 x ds_read_b128);
    // compiler inserts counted lgkmcnt before each dependent MFMA cluster.
    bf16x8 av[4], bv[4], aw[4];
#pragma unroll
    for (int m = 0; m < 4; ++m) {
      const int R = wm * 128 + m * 16 + fr;
      av[m] = *(const bf16x8*)(Ap + R * 32 + ((fg ^ ((R >> 1) & 3)) * 8));
    }
#pragma unroll
    for (int n = 0; n < 4; ++n) {
      const int R = wn * 64 + n * 16 + fr;
      bv[n] = *(const bf16x8*)(Bp + R * 32 + ((fg ^ ((R >> 1) & 3)) * 8));
    }
#pragma unroll
    for (int m = 0; m < 4; ++m) {
      const int R = wm * 128 + 64 + m * 16 + fr;
      aw[m] = *(const bf16x8*)(Ap + R * 32 + ((fg ^ ((R >> 1) & 3)) * 8));
    }

    // stage tile t+3 early: HBM latency hides under this tile's MFMA
    gld16(A + agA0 + ko, Aq + ldsW);
    gld16(A + agA1 + ko, Aq + ldsW + 4096);
    gld16(Bt + agB0 + ko, Bq + ldsW);
    gld16(Bt + agB1 + ko, Bq + ldsW + 4096);

    __builtin_amdgcn_s_setprio(1);
#pragma unroll
    for (int m = 0; m < 4; ++m)
#pragma unroll
      for (int n = 0; n < 4; ++n)
        acc[m][n] = __builtin_amdgcn_mfma_f32_16x16x32_bf16(av[m], bv[n], acc[m][n], 0, 0, 0);
#pragma unroll
    for (int m = 0; m < 4; ++m)
#pragma unroll
      for (int n = 0; n < 4; ++n)
        acc[4 + m][n] = __builtin_amdgcn_mfma_f32_16x16x32_bf16(aw[m], bv[n], acc[4 + m][n], 0, 0, 0);
    __builtin_amdgcn_s_setprio(0);

    // counted drain: oldest 4 (tile t-2's loads, needed at tile t+1) retire; 8 stay in flight.
    // Single barrier per tile: all waves' reads of buf[t&3] completed (consumed by MFMA above);
    // next tile's staging targets buf[(t+4)&3] so no WAR across this barrier.
    asm volatile("s_waitcnt vmcnt(8)" ::: "memory");
    __builtin_amdgcn_s_barrier();
  }

  // epilogue: C/D layout col=lane&15, row=(lane>>4)*4+reg  [m89]
  const int crow0 = bm + wm * 128 + fg * 4;
  const int ccol0 = bn + wn * 64 + fr;
#pragma unroll
  for (int n = 0; n < 4; ++n) {
    const int col = ccol0 + n * 16;
    const float bvl = bias[col];
#pragma unroll
    for (int mf = 0; mf < 8; ++mf) {
      const int r0 = crow0 + mf * 16;
#pragma unroll
      for (int q = 0; q < 4; ++q)
        C[(size_t)(r0 + q) * 4096 + col] = acc[mf][n][q] + bvl;
    }
  }
}

extern "C" void kernel_launch(void* const* d_in, const int* in_sizes, int n_in,
                              void* d_out, int out_size, void* d_ws, size_t ws_size,
                              hipStream_t stream) {
  const float* x    = (const float*)d_in[0];
  const float* ker  = (const float*)d_in[1];
  const float* bias = (const float*)d_in[2];
  float* out = (float*)d_out;

  char* ws = (char*)d_ws;
  u16*  xb    = (u16*)ws;                      // 32 MB  bf16 x
  u16*  wt    = (u16*)(ws + 33554432);         // 32 MB  bf16 W^T
  u16*  w234t = (u16*)(ws + 67108864);         // 16 MB  bf16 W234^T
  float* w34T = (float*)(ws + 83886080);       // 512 KB fp32 W34 transposed

  x_to_bf16   <<<8192, 256, 0, stream>>>(x, xb);
  build_w34T  <<<512, 256, 0, stream>>>(ker, w34T);
  build_w234t2<<<512, 256, 0, stream>>>(ker, w34T, w234t);
  build_wt2   <<<1024, 256, 0, stream>>>(ker, w234t, wt);
  gemm_bt4    <<<256, 512, 0, stream>>>(xb, wt, bias, out);
}